// Round 1
// baseline (547.272 us; speedup 1.0000x reference)
//
#include <hip/hip_runtime.h>
#include <cstdint>

#define B_ 32
#define P_ 65536
#define O_ 32
#define THRESH_ 0.35f
#define VAR0 0.1f
#define VAR1 0.2f
#define LOC_W_ 2.0
#define LANDM_W_ 1.0
#define ALPHA_ 0.25f
#define EPS_ 1e-7f

struct WS {
  unsigned long long gkey[B_ * O_];  // per (b,o): packed (iou_bits<<32)|(~p)
  double acc[4];                     // loss_l, loss_c, loss_landm, n1
};

__global__ void init_ws(WS* ws) {
  int t = blockIdx.x * blockDim.x + threadIdx.x;
  if (t < B_ * O_) ws->gkey[t] = 0ull;
  if (t < 4) ws->acc[t] = 0.0;
}

// ---------------- kernel 1: per-(b,o) argmax over priors --------------------
__global__ __launch_bounds__(256) void k_argmax(const float* __restrict__ priors,
                                                const float* __restrict__ targets,
                                                WS* __restrict__ ws) {
  __shared__ float tx1[O_], ty1[O_], tx2[O_], ty2[O_], tarea[O_];
  __shared__ unsigned long long lkey[O_];
  const int b = blockIdx.y;
  const int tid = threadIdx.x;
  if (tid < O_) {
    const float* trow = targets + ((size_t)b * O_ + tid) * 15;
    float x1 = trow[0], y1 = trow[1], x2 = trow[2], y2 = trow[3];
    tx1[tid] = x1; ty1[tid] = y1; tx2[tid] = x2; ty2[tid] = y2;
    tarea[tid] = (x2 - x1) * (y2 - y1);
    // key for iou==0 at p==0 -> zero-iou lanes never need to atomic
    lkey[tid] = 0xFFFFFFFFull;
  }
  __syncthreads();

  const int p = blockIdx.x * 256 + tid;
  float4 pr = reinterpret_cast<const float4*>(priors)[p];
  float px1 = pr.x - pr.z * 0.5f, py1 = pr.y - pr.w * 0.5f;
  float px2 = pr.x + pr.z * 0.5f, py2 = pr.y + pr.w * 0.5f;
  float parea = (px2 - px1) * (py2 - py1);
  const unsigned int pinv = 0xFFFFFFFFu - (unsigned)p;

  #pragma unroll 8
  for (int o = 0; o < O_; ++o) {
    float ltx = fmaxf(tx1[o], px1), lty = fmaxf(ty1[o], py1);
    float rbx = fminf(tx2[o], px2), rby = fminf(ty2[o], py2);
    float iw = fmaxf(rbx - ltx, 0.f), ih = fmaxf(rby - lty, 0.f);
    float inter = iw * ih;
    float iou = inter / (tarea[o] + parea - inter);
    unsigned long long key =
        ((unsigned long long)__float_as_uint(iou) << 32) | (unsigned long long)pinv;
    if (key > lkey[o]) atomicMax(&lkey[o], key);
  }
  __syncthreads();
  if (tid < O_) atomicMax(&ws->gkey[(size_t)b * O_ + tid], lkey[tid]);
}

// ---------------- kernel 2: matching + losses -------------------------------
__global__ __launch_bounds__(256) void k_loss(const float* __restrict__ loc_data,
                                              const float* __restrict__ conf_data,
                                              const float* __restrict__ landm_data,
                                              const float* __restrict__ priors,
                                              const float* __restrict__ targets,
                                              WS* __restrict__ ws) {
  __shared__ float tx1[O_], ty1[O_], tx2[O_], ty2[O_], tarea[O_], tlbl[O_];
  __shared__ float tlm[O_][10];
  __shared__ unsigned int fprior[O_];
  __shared__ float4 wsum[4];
  const int b = blockIdx.y;
  const int tid = threadIdx.x;
  if (tid < O_) {
    const float* trow = targets + ((size_t)b * O_ + tid) * 15;
    float x1 = trow[0], y1 = trow[1], x2 = trow[2], y2 = trow[3];
    tx1[tid] = x1; ty1[tid] = y1; tx2[tid] = x2; ty2[tid] = y2;
    tarea[tid] = (x2 - x1) * (y2 - y1);
    #pragma unroll
    for (int k = 0; k < 10; ++k) tlm[tid][k] = trow[4 + k];
    tlbl[tid] = trow[14];
    fprior[tid] = 0xFFFFFFFFu - (unsigned)(ws->gkey[(size_t)b * O_ + tid] & 0xFFFFFFFFull);
  }
  __syncthreads();

  const int p = blockIdx.x * 256 + tid;
  float4 pr = reinterpret_cast<const float4*>(priors)[p];
  float px1 = pr.x - pr.z * 0.5f, py1 = pr.y - pr.w * 0.5f;
  float px2 = pr.x + pr.z * 0.5f, py2 = pr.y + pr.w * 0.5f;
  float parea = (px2 - px1) * (py2 - py1);

  // per-prior best truth (first-occurrence argmax)
  float bov = -1.f;
  int bidx = 0;
  #pragma unroll 8
  for (int o = 0; o < O_; ++o) {
    float ltx = fmaxf(tx1[o], px1), lty = fmaxf(ty1[o], py1);
    float rbx = fminf(tx2[o], px2), rby = fminf(ty2[o], py2);
    float iw = fmaxf(rbx - ltx, 0.f), ih = fmaxf(rby - lty, 0.f);
    float inter = iw * ih;
    float iou = inter / (tarea[o] + parea - inter);
    if (iou > bov) { bov = iou; bidx = o; }
  }

  // forced matches: last j wins (XLA sequential scatter semantics)
  int fi = -1;
  #pragma unroll
  for (int j = 0; j < O_; ++j)
    if (fprior[j] == (unsigned)p) fi = j;
  float ov = bov;
  int idx = bidx;
  if (fi >= 0) { idx = fi; ov = 2.0f; }

  const bool pos = !(ov < THRESH_);          // conf_raw != 0
  const bool pos1 = pos && (tlbl[idx] > 0.f);  // conf_raw > 0

  // focal loss (all priors)
  const size_t bp = (size_t)b * P_ + p;
  float2 cf = reinterpret_cast<const float2*>(conf_data)[bp];
  float mx = fmaxf(cf.x, cf.y);
  float lse = mx + logf(expf(cf.x - mx) + expf(cf.y - mx));
  float xt = pos ? cf.y : cf.x;
  float logpt = xt - lse;
  float pt = expf(logpt);
  float om = 1.f - pt;
  float lc = -ALPHA_ * om * sqrtf(om) * logpt;  // (1-pt)^1.5

  float ll = 0.f, llm = 0.f, n1 = 0.f;
  if (pos) {
    float4 loc = reinterpret_cast<const float4*>(loc_data)[bp];
    float dx = pr.x + loc.x * VAR0 * pr.z;
    float dy = pr.y + loc.y * VAR0 * pr.w;
    float dw = pr.z * expf(loc.z * VAR1);
    float dh = pr.w * expf(loc.w * VAR1);
    float b1x1 = dx - dw * 0.5f, b1y1 = dy - dh * 0.5f;
    float b1x2 = dx + dw * 0.5f, b1y2 = dy + dh * 0.5f;
    float b2x1 = tx1[idx], b2y1 = ty1[idx], b2x2 = tx2[idx], b2y2 = ty2[idx];
    float a1 = (b1x2 - b1x1) * (b1y2 - b1y1);
    float a2 = (b2x2 - b2x1) * (b2y2 - b2y1);
    float iw = fmaxf(fminf(b1x2, b2x2) - fmaxf(b1x1, b2x1), 0.f);
    float ih = fmaxf(fminf(b1y2, b2y2) - fmaxf(b1y1, b2y1), 0.f);
    float inter = iw * ih;
    float uni = a1 + a2 - inter;
    float iou = inter / (uni + EPS_);
    float ew = fmaxf(b1x2, b2x2) - fminf(b1x1, b2x1);
    float eh = fmaxf(b1y2, b2y2) - fminf(b1y1, b2y1);
    float enc = ew * eh;
    float g = iou - (enc - uni) / (enc + EPS_);
    ll = 1.f - g;
  }
  if (pos1) {
    n1 = 1.f;
    const float* lmrow = landm_data + bp * 10;
    float rw = 1.f / (VAR0 * pr.z);
    float rh = 1.f / (VAR0 * pr.w);
    #pragma unroll
    for (int q = 0; q < 5; ++q) {
      float2 d = *reinterpret_cast<const float2*>(lmrow + q * 2);
      float gx = (tlm[idx][2 * q] - pr.x) * rw;
      float gy = (tlm[idx][2 * q + 1] - pr.y) * rh;
      float ex = d.x - gx, ey = d.y - gy;
      float ax = fabsf(ex), ay = fabsf(ey);
      llm += (ax < 1.f) ? 0.5f * ex * ex : ax - 0.5f;
      llm += (ay < 1.f) ? 0.5f * ey * ey : ay - 0.5f;
    }
  }

  // block reduce (4 waves of 64)
  float vx = ll, vy = lc, vz = llm, vw = n1;
  #pragma unroll
  for (int i = 32; i > 0; i >>= 1) {
    vx += __shfl_xor(vx, i);
    vy += __shfl_xor(vy, i);
    vz += __shfl_xor(vz, i);
    vw += __shfl_xor(vw, i);
  }
  const int wave = tid >> 6, lane = tid & 63;
  if (lane == 0) wsum[wave] = make_float4(vx, vy, vz, vw);
  __syncthreads();
  if (tid == 0) {
    float sx = 0.f, sy = 0.f, sz = 0.f, sw = 0.f;
    #pragma unroll
    for (int w = 0; w < 4; ++w) {
      sx += wsum[w].x; sy += wsum[w].y; sz += wsum[w].z; sw += wsum[w].w;
    }
    atomicAdd(&ws->acc[0], (double)sx);
    atomicAdd(&ws->acc[1], (double)sy);
    atomicAdd(&ws->acc[2], (double)sz);
    atomicAdd(&ws->acc[3], (double)sw);
  }
}

__global__ void k_final(const WS* __restrict__ ws, float* __restrict__ out) {
  double n1 = ws->acc[3];
  if (n1 < 1.0) n1 = 1.0;
  out[0] = (float)(LOC_W_ * ws->acc[0] / n1);
  out[1] = (float)(ws->acc[1] / n1);
  out[2] = (float)(LANDM_W_ * ws->acc[2] / n1);
}

extern "C" void kernel_launch(void* const* d_in, const int* in_sizes, int n_in,
                              void* d_out, int out_size, void* d_ws, size_t ws_size,
                              hipStream_t stream) {
  (void)in_sizes; (void)n_in; (void)out_size; (void)ws_size;
  const float* loc     = (const float*)d_in[0];
  const float* conf    = (const float*)d_in[1];
  const float* landm   = (const float*)d_in[2];
  const float* priors  = (const float*)d_in[3];
  const float* targets = (const float*)d_in[4];
  WS* ws = (WS*)d_ws;
  float* out = (float*)d_out;

  hipLaunchKernelGGL(init_ws, dim3(5), dim3(256), 0, stream, ws);
  dim3 grid(P_ / 256, B_);
  hipLaunchKernelGGL(k_argmax, grid, dim3(256), 0, stream, priors, targets, ws);
  hipLaunchKernelGGL(k_loss, grid, dim3(256), 0, stream,
                     loc, conf, landm, priors, targets, ws);
  hipLaunchKernelGGL(k_final, dim3(1), dim3(1), 0, stream, ws, out);
}

// Round 2
// 155.539 us; speedup vs baseline: 3.5185x; 3.5185x over previous
//
#include <hip/hip_runtime.h>
#include <cstdint>

#define B_ 32
#define P_ 65536
#define O_ 32
#define GX_ 64            // grid.x for main kernels; each block handles P_/256/GX_ = 4 chunks
#define NCHUNK_ (P_ / 256)
#define THRESH_ 0.35f
#define VAR0 0.1f
#define VAR1 0.2f
#define EPS_ 1e-7f
#define ALPHA_ 0.25f

struct WS {
  unsigned long long gkey[B_ * O_];  // per (b,o): packed (iou_bits<<32)|(~p)
  float4 part[GX_ * B_];             // per-block partial sums (ll, lc, llm, n1)
};

__global__ void init_ws(WS* ws) {
  int t = blockIdx.x * blockDim.x + threadIdx.x;
  if (t < B_ * O_) ws->gkey[t] = 0ull;
}

// ---------------- kernel 1: per-(b,o) argmax over priors --------------------
__global__ __launch_bounds__(256) void k_argmax(const float* __restrict__ priors,
                                                const float* __restrict__ targets,
                                                WS* __restrict__ ws) {
  __shared__ float tx1[O_], ty1[O_], tx2[O_], ty2[O_], tarea[O_];
  __shared__ unsigned long long lkey[O_];
  const int b = blockIdx.y;
  const int tid = threadIdx.x;
  if (tid < O_) {
    const float* trow = targets + ((size_t)b * O_ + tid) * 15;
    float x1 = trow[0], y1 = trow[1], x2 = trow[2], y2 = trow[3];
    tx1[tid] = x1; ty1[tid] = y1; tx2[tid] = x2; ty2[tid] = y2;
    tarea[tid] = (x2 - x1) * (y2 - y1);
    // key for iou==0 at p==0 -> zero-iou lanes never need to atomic
    lkey[tid] = 0xFFFFFFFFull;
  }
  __syncthreads();

  for (int c = blockIdx.x; c < NCHUNK_; c += GX_) {
    const int p = c * 256 + tid;
    float4 pr = reinterpret_cast<const float4*>(priors)[p];
    float px1 = pr.x - pr.z * 0.5f, py1 = pr.y - pr.w * 0.5f;
    float px2 = pr.x + pr.z * 0.5f, py2 = pr.y + pr.w * 0.5f;
    float parea = (px2 - px1) * (py2 - py1);
    const unsigned int pinv = 0xFFFFFFFFu - (unsigned)p;

    #pragma unroll 8
    for (int o = 0; o < O_; ++o) {
      float ltx = fmaxf(tx1[o], px1), lty = fmaxf(ty1[o], py1);
      float rbx = fminf(tx2[o], px2), rby = fminf(ty2[o], py2);
      float iw = fmaxf(rbx - ltx, 0.f), ih = fmaxf(rby - lty, 0.f);
      float inter = iw * ih;
      float iou = inter / (tarea[o] + parea - inter);
      unsigned long long key =
          ((unsigned long long)__float_as_uint(iou) << 32) | (unsigned long long)pinv;
      if (key > lkey[o]) atomicMax(&lkey[o], key);
    }
  }
  __syncthreads();
  if (tid < O_) atomicMax(&ws->gkey[(size_t)b * O_ + tid], lkey[tid]);
}

// ---------------- kernel 2: matching + losses -------------------------------
__global__ __launch_bounds__(256) void k_loss(const float* __restrict__ loc_data,
                                              const float* __restrict__ conf_data,
                                              const float* __restrict__ landm_data,
                                              const float* __restrict__ priors,
                                              const float* __restrict__ targets,
                                              WS* __restrict__ ws) {
  __shared__ float tx1[O_], ty1[O_], tx2[O_], ty2[O_], tarea[O_], tlbl[O_];
  __shared__ float tlm[O_][10];
  __shared__ unsigned int fprior[O_];
  __shared__ float4 wsum[4];
  const int b = blockIdx.y;
  const int tid = threadIdx.x;
  if (tid < O_) {
    const float* trow = targets + ((size_t)b * O_ + tid) * 15;
    float x1 = trow[0], y1 = trow[1], x2 = trow[2], y2 = trow[3];
    tx1[tid] = x1; ty1[tid] = y1; tx2[tid] = x2; ty2[tid] = y2;
    tarea[tid] = (x2 - x1) * (y2 - y1);
    #pragma unroll
    for (int k = 0; k < 10; ++k) tlm[tid][k] = trow[4 + k];
    tlbl[tid] = trow[14];
    fprior[tid] = 0xFFFFFFFFu - (unsigned)(ws->gkey[(size_t)b * O_ + tid] & 0xFFFFFFFFull);
  }
  __syncthreads();

  float vx = 0.f, vy = 0.f, vz = 0.f, vw = 0.f;

  for (int c = blockIdx.x; c < NCHUNK_; c += GX_) {
    const int p = c * 256 + tid;
    float4 pr = reinterpret_cast<const float4*>(priors)[p];
    float px1 = pr.x - pr.z * 0.5f, py1 = pr.y - pr.w * 0.5f;
    float px2 = pr.x + pr.z * 0.5f, py2 = pr.y + pr.w * 0.5f;
    float parea = (px2 - px1) * (py2 - py1);

    // per-prior best truth (first-occurrence argmax)
    float bov = -1.f;
    int bidx = 0;
    #pragma unroll 8
    for (int o = 0; o < O_; ++o) {
      float ltx = fmaxf(tx1[o], px1), lty = fmaxf(ty1[o], py1);
      float rbx = fminf(tx2[o], px2), rby = fminf(ty2[o], py2);
      float iw = fmaxf(rbx - ltx, 0.f), ih = fmaxf(rby - lty, 0.f);
      float inter = iw * ih;
      float iou = inter / (tarea[o] + parea - inter);
      if (iou > bov) { bov = iou; bidx = o; }
    }

    // forced matches: last j wins (XLA sequential scatter semantics)
    int fi = -1;
    #pragma unroll
    for (int j = 0; j < O_; ++j)
      if (fprior[j] == (unsigned)p) fi = j;
    float ov = bov;
    int idx = bidx;
    if (fi >= 0) { idx = fi; ov = 2.0f; }

    const bool pos = !(ov < THRESH_);            // conf_raw != 0
    const bool pos1 = pos && (tlbl[idx] > 0.f);  // conf_raw > 0

    // focal loss (all priors) — fast hw exp/log
    const size_t bp = (size_t)b * P_ + p;
    float2 cf = reinterpret_cast<const float2*>(conf_data)[bp];
    float mx = fmaxf(cf.x, cf.y);
    float lse = mx + __logf(1.f + __expf(-fabsf(cf.x - cf.y)));
    float xt = pos ? cf.y : cf.x;
    float logpt = xt - lse;
    float pt = __expf(logpt);
    float om = 1.f - pt;
    vy += -ALPHA_ * om * sqrtf(om) * logpt;  // (1-pt)^1.5

    if (pos) {
      float4 loc = reinterpret_cast<const float4*>(loc_data)[bp];
      float dx = pr.x + loc.x * VAR0 * pr.z;
      float dy = pr.y + loc.y * VAR0 * pr.w;
      float dw = pr.z * __expf(loc.z * VAR1);
      float dh = pr.w * __expf(loc.w * VAR1);
      float b1x1 = dx - dw * 0.5f, b1y1 = dy - dh * 0.5f;
      float b1x2 = dx + dw * 0.5f, b1y2 = dy + dh * 0.5f;
      float b2x1 = tx1[idx], b2y1 = ty1[idx], b2x2 = tx2[idx], b2y2 = ty2[idx];
      float a1 = (b1x2 - b1x1) * (b1y2 - b1y1);
      float a2 = (b2x2 - b2x1) * (b2y2 - b2y1);
      float iw = fmaxf(fminf(b1x2, b2x2) - fmaxf(b1x1, b2x1), 0.f);
      float ih = fmaxf(fminf(b1y2, b2y2) - fmaxf(b1y1, b2y1), 0.f);
      float inter = iw * ih;
      float uni = a1 + a2 - inter;
      float iou = inter / (uni + EPS_);
      float ew = fmaxf(b1x2, b2x2) - fminf(b1x1, b2x1);
      float eh = fmaxf(b1y2, b2y2) - fminf(b1y1, b2y1);
      float enc = ew * eh;
      float g = iou - (enc - uni) / (enc + EPS_);
      vx += 1.f - g;
    }
    if (pos1) {
      vw += 1.f;
      const float* lmrow = landm_data + bp * 10;
      float rw = 1.f / (VAR0 * pr.z);
      float rh = 1.f / (VAR0 * pr.w);
      float llm = 0.f;
      #pragma unroll
      for (int q = 0; q < 5; ++q) {
        float2 d = *reinterpret_cast<const float2*>(lmrow + q * 2);
        float gx = (tlm[idx][2 * q] - pr.x) * rw;
        float gy = (tlm[idx][2 * q + 1] - pr.y) * rh;
        float ex = d.x - gx, ey = d.y - gy;
        float ax = fabsf(ex), ay = fabsf(ey);
        llm += (ax < 1.f) ? 0.5f * ex * ex : ax - 0.5f;
        llm += (ay < 1.f) ? 0.5f * ey * ey : ay - 0.5f;
      }
      vz += llm;
    }
  }

  // block reduce (4 waves of 64) -> one float4 partial per block, NO atomics
  #pragma unroll
  for (int i = 32; i > 0; i >>= 1) {
    vx += __shfl_xor(vx, i);
    vy += __shfl_xor(vy, i);
    vz += __shfl_xor(vz, i);
    vw += __shfl_xor(vw, i);
  }
  const int wave = tid >> 6, lane = tid & 63;
  if (lane == 0) wsum[wave] = make_float4(vx, vy, vz, vw);
  __syncthreads();
  if (tid == 0) {
    float sx = 0.f, sy = 0.f, sz = 0.f, sw = 0.f;
    #pragma unroll
    for (int w = 0; w < 4; ++w) {
      sx += wsum[w].x; sy += wsum[w].y; sz += wsum[w].z; sw += wsum[w].w;
    }
    ws->part[(size_t)blockIdx.y * GX_ + blockIdx.x] = make_float4(sx, sy, sz, sw);
  }
}

// ---------------- kernel 3: final reduction ---------------------------------
__global__ __launch_bounds__(256) void k_final(const WS* __restrict__ ws,
                                               float* __restrict__ out) {
  __shared__ double sh[4][4];
  const int tid = threadIdx.x;
  double sx = 0.0, sy = 0.0, sz = 0.0, sw = 0.0;
  for (int i = tid; i < GX_ * B_; i += 256) {
    float4 v = ws->part[i];
    sx += v.x; sy += v.y; sz += v.z; sw += v.w;
  }
  #pragma unroll
  for (int i = 32; i > 0; i >>= 1) {
    sx += __shfl_xor(sx, i);
    sy += __shfl_xor(sy, i);
    sz += __shfl_xor(sz, i);
    sw += __shfl_xor(sw, i);
  }
  const int wave = tid >> 6, lane = tid & 63;
  if (lane == 0) { sh[wave][0] = sx; sh[wave][1] = sy; sh[wave][2] = sz; sh[wave][3] = sw; }
  __syncthreads();
  if (tid == 0) {
    double ax = 0, ay = 0, az = 0, aw = 0;
    #pragma unroll
    for (int w = 0; w < 4; ++w) { ax += sh[w][0]; ay += sh[w][1]; az += sh[w][2]; aw += sh[w][3]; }
    double n1 = aw < 1.0 ? 1.0 : aw;
    out[0] = (float)(2.0 * ax / n1);  // LOC_W
    out[1] = (float)(ay / n1);
    out[2] = (float)(az / n1);        // LANDM_W
  }
}

extern "C" void kernel_launch(void* const* d_in, const int* in_sizes, int n_in,
                              void* d_out, int out_size, void* d_ws, size_t ws_size,
                              hipStream_t stream) {
  (void)in_sizes; (void)n_in; (void)out_size; (void)ws_size;
  const float* loc     = (const float*)d_in[0];
  const float* conf    = (const float*)d_in[1];
  const float* landm   = (const float*)d_in[2];
  const float* priors  = (const float*)d_in[3];
  const float* targets = (const float*)d_in[4];
  WS* ws = (WS*)d_ws;
  float* out = (float*)d_out;

  hipLaunchKernelGGL(init_ws, dim3(4), dim3(256), 0, stream, ws);
  dim3 grid(GX_, B_);
  hipLaunchKernelGGL(k_argmax, grid, dim3(256), 0, stream, priors, targets, ws);
  hipLaunchKernelGGL(k_loss, grid, dim3(256), 0, stream,
                     loc, conf, landm, priors, targets, ws);
  hipLaunchKernelGGL(k_final, dim3(1), dim3(256), 0, stream, ws, out);
}